// Round 2
// 852.044 us; speedup vs baseline: 1.0931x; 1.0931x over previous
//
#include <hip/hip_runtime.h>
#include <math.h>

#define N_NODES 100000
#define N_EDGES 1200000
#define GC 64
#define RBF 32
#define NLAYERS 4
#define NF 92
#define NATOM 100
#define BN_EPS 1e-5f
#define TILE_GRID 2048
#define NWIN (N_EDGES / 16)     // 75000 windows, exact (E % 16 == 0)
#define LOG2E 1.44269504f
#define LN2 0.69314718f

typedef _Float16 half8 __attribute__((ext_vector_type(8)));
typedef _Float16 half4 __attribute__((ext_vector_type(4)));
typedef float f32x4 __attribute__((ext_vector_type(4)));

// ---------- K1: degree histogram ----------
__global__ __launch_bounds__(256) void deg_kernel(
    const int* __restrict__ ei, int* __restrict__ deg)
{
    int e = blockIdx.x * 256 + threadIdx.x;
    if (e >= N_EDGES) return;
    atomicAdd(&deg[ei[N_EDGES + e]], 1);
}

// ---------- scan ----------
__global__ __launch_bounds__(256) void scan_a_kernel(const int* __restrict__ deg, int* __restrict__ bsums)
{
    __shared__ int sm[256];
    int tid = threadIdx.x;
    int i = blockIdx.x * 256 + tid;
    int v = (i < N_NODES) ? deg[i] : 0;
    sm[tid] = v;
    __syncthreads();
    for (int s = 128; s > 0; s >>= 1) {
        if (tid < s) sm[tid] += sm[tid + s];
        __syncthreads();
    }
    if (tid == 0) bsums[blockIdx.x] = sm[0];
}

__global__ __launch_bounds__(512) void scan_b_kernel(const int* __restrict__ bsums, int* __restrict__ boffs)
{
    __shared__ int sm[512];
    int tid = threadIdx.x;
    int v = (tid < 391) ? bsums[tid] : 0;
    sm[tid] = v;
    __syncthreads();
    for (int off = 1; off < 512; off <<= 1) {
        int t = (tid >= off) ? sm[tid - off] : 0;
        __syncthreads();
        sm[tid] += t;
        __syncthreads();
    }
    boffs[tid] = (tid == 0) ? 0 : sm[tid - 1];
}

__global__ __launch_bounds__(256) void scan_c_kernel(
    const int* __restrict__ deg, const int* __restrict__ boffs,
    int* __restrict__ row_st, float* __restrict__ inv_deg)
{
    __shared__ int sm[256];
    int tid = threadIdx.x;
    int i = blockIdx.x * 256 + tid;
    int v = (i < N_NODES) ? deg[i] : 0;
    sm[tid] = v;
    __syncthreads();
    for (int off = 1; off < 256; off <<= 1) {
        int t = (tid >= off) ? sm[tid - off] : 0;
        __syncthreads();
        sm[tid] += t;
        __syncthreads();
    }
    if (i <= N_NODES) row_st[i] = boffs[blockIdx.x] + sm[tid] - v;  // exclusive
    if (i < N_NODES) inv_deg[i] = (v > 0) ? (1.0f / (float)v) : 0.0f;
}

// ---------- K2a: scatter edges into CSR order ----------
__global__ __launch_bounds__(256) void scatter_perm_kernel(
    const int* __restrict__ ei, const int* __restrict__ row_st,
    int* __restrict__ cursor, int* __restrict__ csr_src, int* __restrict__ csr_dst)
{
    int e = blockIdx.x * 256 + threadIdx.x;
    if (e >= N_EDGES) return;
    int s = ei[e];
    int d = ei[N_EDGES + e];
    int p = atomicAdd(&cursor[d], 1);
    int idx = row_st[d] + p;
    csr_src[idx] = s;
    csr_dst[idx] = d;
}

// ---------- K2b: RBF in CSR order (coalesced ea writes) ----------
__global__ __launch_bounds__(256) void rbf_kernel(
    const int* __restrict__ csr_src, const int* __restrict__ csr_dst,
    const float* __restrict__ pos,
    const float* __restrict__ means, const float* __restrict__ betas,
    unsigned int* __restrict__ ea)
{
    int idx = blockIdx.x * 256 + threadIdx.x;
    if (idx >= N_EDGES) return;
    int s = csr_src[idx];
    int d = csr_dst[idx];
    float dx = pos[s * 3 + 0] - pos[d * 3 + 0];
    float dy = pos[s * 3 + 1] - pos[d * 3 + 1];
    float dz = pos[s * 3 + 2] - pos[d * 3 + 2];
    float dist = sqrtf(dx * dx + dy * dy + dz * dz + 1e-12f);

    float cut = 0.0f;
    if (dist < 5.0f) cut = 0.5f * (__cosf(dist * 0.6283185307179586f) + 1.0f);
    float ex = __expf(-dist);
    union { _Float16 h[32]; uint4 u[4]; } pk;
#pragma unroll
    for (int k = 0; k < 32; k++) {
        float v = ex - means[k];
        pk.h[k] = (_Float16)(cut * __expf(-betas[k] * v * v));
    }
    uint4* op = (uint4*)(ea + (size_t)idx * 16);
    op[0] = pk.u[0];
    op[1] = pk.u[1];
    op[2] = pk.u[2];
    op[3] = pk.u[3];
}

// ---------- K3: per-window segment metadata ----------
// seg8[e]  : segment id (0..15) of edge e within its window
// wnode[w*16+m] : dst node of segment m (or -1)
// inv_e[e] : inv_deg[dst(e)] * ln2 as f16 (ln2 folds the log2-domain softplus back)
__global__ __launch_bounds__(256) void window_prep_kernel(
    const int* __restrict__ csr_dst, const float* __restrict__ inv_deg,
    unsigned char* __restrict__ seg8, int* __restrict__ wnode, _Float16* __restrict__ inv_e)
{
    int w = blockIdx.x * 256 + threadIdx.x;
    if (w >= NWIN) return;
    int base = w * 16;
    int prev = -1, s = -1;
    for (int k = 0; k < 16; k++) {
        int d = csr_dst[base + k];
        if (d != prev) { s++; prev = d; wnode[base + s] = d; }
        seg8[base + k] = (unsigned char)s;
        inv_e[base + k] = (_Float16)(inv_deg[d] * LN2);
    }
    for (int m = s + 1; m < 16; m++) wnode[base + m] = -1;
}

// ---------- K3b: weights -> f16, transposed [layer][col][k], prescaled by log2(e) ----------
__global__ __launch_bounds__(256) void wcvt_kernel(
    const float* __restrict__ Wf, const float* __restrict__ Ws,
    _Float16* __restrict__ wf16, _Float16* __restrict__ ws16)
{
    int i = blockIdx.x * 256 + threadIdx.x;   // NLAYERS*160*64 = 40960 exact
    int l = i / (160 * GC);
    int r = i - l * 160 * GC;
    int k = r >> 6;
    int col = r & 63;
    size_t o = ((size_t)l * GC + col) * 160 + k;
    wf16[o] = (_Float16)(Wf[i] * LOG2E);
    ws16[o] = (_Float16)(Ws[i] * LOG2E);
}

// ---------- K4a: per-atom-type pre-layer table ----------
__global__ __launch_bounds__(64) void atom_table_kernel(
    const float* __restrict__ emb, const float* __restrict__ pre_W,
    const float* __restrict__ pre_b, float* __restrict__ T)
{
    int a = blockIdx.x;
    int c = threadIdx.x;
    float acc = pre_b[c];
    for (int k = 0; k < NF; k++) acc = fmaf(emb[a * NF + k], pre_W[k * GC + c], acc);
    T[a * GC + c] = fmaxf(acc, 0.0f);
}

// ---------- K4b: broadcast table to nodes ----------
__global__ __launch_bounds__(256) void xinit_kernel(
    const int* __restrict__ atom_types, const float* __restrict__ T,
    float* __restrict__ x, _Float16* __restrict__ x16)
{
    int i = blockIdx.x * 256 + threadIdx.x;  // i < N*16
    int n = i >> 4;
    int a = atom_types[n];
    float4 v = ((const float4*)T)[a * 16 + (i & 15)];
    ((float4*)x)[i] = v;
    half4 h = { (_Float16)v.x, (_Float16)v.y, (_Float16)v.z, (_Float16)v.w };
    ((half4*)x16)[i] = h;
}

// ---------- window compute body ----------
// Full K=160 via MFMA: z = [x_dst(0..63), x_src(64..127), rbf(128..159)].
// Segmented mean-aggregation via masked 16x16x16 f16 MFMA (mask carries inv_deg*ln2).
static __device__ __forceinline__ void compute_win(
    half8 D0, half8 D1, half8 S0, half8 S1, half8 E, int moff,
    const half8 (&WGF)[5][2], const half8 (&WGS)[5][2],
    const float (&biasf)[2], const float (&biass)[2],
    int r16, int quad, int cb,
    const unsigned char* __restrict__ seg8, const int* __restrict__ wnode,
    const _Float16* __restrict__ inv_e, float* __restrict__ x)
{
    // meta loads issued at entry; consumed only after the MFMA+activation block
    unsigned int segq = *(const unsigned int*)(seg8 + moff + quad * 4);
    int4 wn4 = *(const int4*)(wnode + moff + quad * 4);
    half4 inv4 = *(const half4*)(inv_e + moff + quad * 4);

    f32x4 accf[2], accs[2];
#pragma unroll
    for (int ctl = 0; ctl < 2; ctl++) {
        accf[ctl] = (f32x4){biasf[ctl], biasf[ctl], biasf[ctl], biasf[ctl]};
        accs[ctl] = (f32x4){biass[ctl], biass[ctl], biass[ctl], biass[ctl]};
    }
#pragma unroll
    for (int ctl = 0; ctl < 2; ctl++) {
        accf[ctl] = __builtin_amdgcn_mfma_f32_16x16x32_f16(D0, WGF[0][ctl], accf[ctl], 0, 0, 0);
        accs[ctl] = __builtin_amdgcn_mfma_f32_16x16x32_f16(D0, WGS[0][ctl], accs[ctl], 0, 0, 0);
        accf[ctl] = __builtin_amdgcn_mfma_f32_16x16x32_f16(D1, WGF[1][ctl], accf[ctl], 0, 0, 0);
        accs[ctl] = __builtin_amdgcn_mfma_f32_16x16x32_f16(D1, WGS[1][ctl], accs[ctl], 0, 0, 0);
        accf[ctl] = __builtin_amdgcn_mfma_f32_16x16x32_f16(S0, WGF[2][ctl], accf[ctl], 0, 0, 0);
        accs[ctl] = __builtin_amdgcn_mfma_f32_16x16x32_f16(S0, WGS[2][ctl], accs[ctl], 0, 0, 0);
        accf[ctl] = __builtin_amdgcn_mfma_f32_16x16x32_f16(S1, WGF[3][ctl], accf[ctl], 0, 0, 0);
        accs[ctl] = __builtin_amdgcn_mfma_f32_16x16x32_f16(S1, WGS[3][ctl], accs[ctl], 0, 0, 0);
        accf[ctl] = __builtin_amdgcn_mfma_f32_16x16x32_f16(E,  WGF[4][ctl], accf[ctl], 0, 0, 0);
        accs[ctl] = __builtin_amdgcn_mfma_f32_16x16x32_f16(E,  WGS[4][ctl], accs[ctl], 0, 0, 0);
    }
    // activation in log2 domain (weights prescaled by log2e):
    //   sigmoid(F) = rcp(1 + 2^-F')       softplus(S) = ln2*(max(S',0)+log2(1+2^-|S'|))
    // the ln2 is folded into inv_e.
    half4 msgh[2];
#pragma unroll
    for (int ctl = 0; ctl < 2; ctl++) {
#pragma unroll
        for (int rr = 0; rr < 4; rr++) {
            float af = accf[ctl][rr];
            float as = accs[ctl][rr];
            float sg = __builtin_amdgcn_rcpf(1.0f + __builtin_amdgcn_exp2f(-af));
            float sp = fmaxf(as, 0.0f)
                     + __builtin_amdgcn_logf(1.0f + __builtin_amdgcn_exp2f(-__builtin_fabsf(as)));
            msgh[ctl][rr] = (_Float16)(sg * sp);
        }
    }
    // segment mask fragment: A[m=r16][k=quad*4+j] = (seg(k)==m) ? inv_deg(k)*ln2 : 0
    half4 am;
#pragma unroll
    for (int j = 0; j < 4; j++) {
        int sj = (segq >> (8 * j)) & 0xff;
        am[j] = (sj == r16) ? inv4[j] : (_Float16)0.0f;
    }
    int wa[4] = { wn4.x, wn4.y, wn4.z, wn4.w };
    const f32x4 zf = (f32x4){0.0f, 0.0f, 0.0f, 0.0f};
#pragma unroll
    for (int ctl = 0; ctl < 2; ctl++) {
        f32x4 red = __builtin_amdgcn_mfma_f32_16x16x16f16(am, msgh[ctl], zf, 0, 0, 0);
#pragma unroll
        for (int rr = 0; rr < 4; rr++) {
            int nd = wa[rr];
            if (nd >= 0) atomicAdd(&x[(size_t)nd * GC + cb + ctl * 16 + r16], red[rr]);
        }
    }
}

#define LOADFRAGS(P0_, P1_, Q0_, Q1_, EE_, SRC_, DST_, WW_)                          \
    P0_ = *(const half8*)(x16 + (size_t)(DST_) * GC + quad * 8);                     \
    P1_ = *(const half8*)(x16 + (size_t)(DST_) * GC + 32 + quad * 8);                \
    Q0_ = *(const half8*)(x16 + (size_t)(SRC_) * GC + quad * 8);                     \
    Q1_ = *(const half8*)(x16 + (size_t)(SRC_) * GC + 32 + quad * 8);                \
    EE_ = *(const half8*)(ea + ((size_t)(WW_) * 16 + r16) * RBF + quad * 8);

// ---------- K5: window MFMA CGConv layer ----------
__global__ __launch_bounds__(256, 3) void win_mfma_kernel(
    const _Float16* __restrict__ x16, const _Float16* __restrict__ ea,
    const int* __restrict__ csr_src, const int* __restrict__ csr_dst,
    const unsigned char* __restrict__ seg8, const int* __restrict__ wnode,
    const _Float16* __restrict__ inv_e,
    const _Float16* __restrict__ wf16, const _Float16* __restrict__ ws16, // [64][160] prescaled
    const float* __restrict__ bfv, const float* __restrict__ bsv,
    float* __restrict__ x)
{
    const int lane = threadIdx.x & 63;
    const int wid = threadIdx.x >> 6;
    const int quad = lane >> 4;
    const int r16 = lane & 15;
    const int wgid = blockIdx.x * 4 + wid;
    const int cb = (wgid & 1) * 32;
    int w = wgid >> 1;
    const int NSEQ = TILE_GRID * 2;

    // resident weight fragments: 5 K-tiles x 2 ctl halves, f16 vector loads
    half8 WGF[5][2], WGS[5][2];
#pragma unroll
    for (int ctl = 0; ctl < 2; ctl++) {
        const _Float16* wfp = wf16 + (size_t)(cb + ctl * 16 + r16) * 160 + quad * 8;
        const _Float16* wsp = ws16 + (size_t)(cb + ctl * 16 + r16) * 160 + quad * 8;
#pragma unroll
        for (int kt = 0; kt < 5; kt++) {
            WGF[kt][ctl] = *(const half8*)(wfp + kt * 32);
            WGS[kt][ctl] = *(const half8*)(wsp + kt * 32);
        }
    }
    float biasf[2], biass[2];
#pragma unroll
    for (int ctl = 0; ctl < 2; ctl++) {
        int col = cb + ctl * 16 + r16;
        biasf[ctl] = bfv[col] * LOG2E;
        biass[ctl] = bsv[col] * LOG2E;
    }

    // ---- prologue: frags A = window w, frags B = w+N, addrs C = w+2N ----
    int sA = csr_src[w * 16 + r16];
    int dA = csr_dst[w * 16 + r16];
    half8 AD0, AD1, AS0, AS1, AE;
    LOADFRAGS(AD0, AD1, AS0, AS1, AE, sA, dA, w);
    int moffA = w * 16;

    int wB = w + NSEQ; if (wB >= NWIN) wB = NWIN - 1;
    int sB = csr_src[wB * 16 + r16];
    int dB = csr_dst[wB * 16 + r16];
    half8 BD0, BD1, BQ0, BQ1, BE;
    LOADFRAGS(BD0, BD1, BQ0, BQ1, BE, sB, dB, wB);
    int moffB = wB * 16;

    int wC = wB + NSEQ; if (wC >= NWIN) wC = NWIN - 1;
    int sC = csr_src[wC * 16 + r16];
    int dC = csr_dst[wC * 16 + r16];

    while (true) {
        compute_win(AD0, AD1, AS0, AS1, AE, moffA, WGF, WGS, biasf, biass,
                    r16, quad, cb, seg8, wnode, inv_e, x);
        LOADFRAGS(AD0, AD1, AS0, AS1, AE, sC, dC, wC);
        moffA = wC * 16;
        wC += NSEQ; if (wC >= NWIN) wC = NWIN - 1;
        sC = csr_src[wC * 16 + r16];
        dC = csr_dst[wC * 16 + r16];
        w += NSEQ;
        if (w >= NWIN) break;

        compute_win(BD0, BD1, BQ0, BQ1, BE, moffB, WGF, WGS, biasf, biass,
                    r16, quad, cb, seg8, wnode, inv_e, x);
        LOADFRAGS(BD0, BD1, BQ0, BQ1, BE, sC, dC, wC);
        moffB = wC * 16;
        wC += NSEQ; if (wC >= NWIN) wC = NWIN - 1;
        sC = csr_src[wC * 16 + r16];
        dC = csr_dst[wC * 16 + r16];
        w += NSEQ;
        if (w >= NWIN) break;
    }
}

// ---------- K6: BN stats ----------
__global__ __launch_bounds__(256) void stats_kernel(const float* __restrict__ x, float* __restrict__ stats)
{
    const int lane = threadIdx.x & 63;
    const int wid = threadIdx.x >> 6;
    int w = blockIdx.x * 4 + wid;
    float s1 = 0.0f, s2 = 0.0f;
    for (int n = w; n < N_NODES; n += 1024) {
        float v = x[(size_t)n * GC + lane];
        s1 += v;
        s2 = fmaf(v, v, s2);
    }
    __shared__ float rs1[4][64];
    __shared__ float rs2[4][64];
    rs1[wid][lane] = s1;
    rs2[wid][lane] = s2;
    __syncthreads();
    if (threadIdx.x < 64) {
        atomicAdd(&stats[lane], rs1[0][lane] + rs1[1][lane] + rs1[2][lane] + rs1[3][lane]);
    } else if (threadIdx.x < 128) {
        int c = threadIdx.x & 63;
        atomicAdd(&stats[64 + c], rs2[0][c] + rs2[1][c] + rs2[2][c] + rs2[3][c]);
    }
}

// ---------- K7a: BN apply + refresh x16 (layers 0..2) ----------
__global__ __launch_bounds__(256) void bn_x16_kernel(
    const float* __restrict__ xn, const float* __restrict__ stats,
    const float* __restrict__ gamma, const float* __restrict__ beta,
    float* __restrict__ xout, _Float16* __restrict__ x16)
{
    int i = blockIdx.x * 256 + threadIdx.x;
    int c4 = (i & 15) * 4;
    float4 v = ((const float4*)xn)[i];
    float vv[4] = {v.x, v.y, v.z, v.w};
    float o[4];
    const float invN = 1.0f / (float)N_NODES;
#pragma unroll
    for (int t = 0; t < 4; t++) {
        int c = c4 + t;
        float mu = stats[c] * invN;
        float var = stats[64 + c] * invN - mu * mu;
        float sc = gamma[c] * rsqrtf(var + BN_EPS);
        o[t] = (vv[t] - mu) * sc + beta[c];
    }
    ((float4*)xout)[i] = make_float4(o[0], o[1], o[2], o[3]);
    half4 h = { (_Float16)o[0], (_Float16)o[1], (_Float16)o[2], (_Float16)o[3] };
    ((half4*)x16)[i] = h;
}

// ---------- K7b: final batchnorm apply (layer 3 -> d_out) ----------
__global__ __launch_bounds__(256) void bn_kernel(
    const float* __restrict__ xn, const float* __restrict__ stats,
    const float* __restrict__ gamma, const float* __restrict__ beta,
    float* __restrict__ out)
{
    int i = blockIdx.x * 256 + threadIdx.x;
    int c4 = (i & 15) * 4;
    float4 v = ((const float4*)xn)[i];
    float vv[4] = {v.x, v.y, v.z, v.w};
    float o[4];
    const float invN = 1.0f / (float)N_NODES;
#pragma unroll
    for (int t = 0; t < 4; t++) {
        int c = c4 + t;
        float mu = stats[c] * invN;
        float var = stats[64 + c] * invN - mu * mu;
        float sc = gamma[c] * rsqrtf(var + BN_EPS);
        o[t] = (vv[t] - mu) * sc + beta[c];
    }
    ((float4*)out)[i] = make_float4(o[0], o[1], o[2], o[3]);
}

extern "C" void kernel_launch(void* const* d_in, const int* in_sizes, int n_in,
                              void* d_out, int out_size, void* d_ws, size_t ws_size,
                              hipStream_t stream)
{
    const int* atom_types = (const int*)d_in[0];
    const float* pos = (const float*)d_in[1];
    const int* edge_index = (const int*)d_in[2];
    const float* emb = (const float*)d_in[3];
    const float* pre_W = (const float*)d_in[4];
    const float* pre_b = (const float*)d_in[5];
    const float* Wf = (const float*)d_in[6];
    const float* bf = (const float*)d_in[7];
    const float* Ws = (const float*)d_in[8];
    const float* bs = (const float*)d_in[9];
    const float* gamma = (const float*)d_in[10];
    const float* beta = (const float*)d_in[11];
    const float* means = (const float*)d_in[12];
    const float* betas = (const float*)d_in[13];

    char* base = (char*)d_ws;
    char* p = base;
    auto alloc = [&](size_t bytes) -> char* {
        char* r = p;
        p += (bytes + 255) & ~(size_t)255;
        return r;
    };
    unsigned int* ea = (unsigned int*)alloc((size_t)N_EDGES * RBF * 2);    // 76.8 MB fp16
    float* x = (float*)alloc((size_t)N_NODES * GC * 4);                    // 25.6 MB
    _Float16* x16 = (_Float16*)alloc((size_t)N_NODES * GC * 2);            // 12.8 MB
    int* csr_src = (int*)alloc((size_t)N_EDGES * 4);                       // 4.8 MB
    int* csr_dst = (int*)alloc((size_t)N_EDGES * 4);                       // 4.8 MB
    int* wnode = (int*)alloc((size_t)N_EDGES * 4);                         // 4.8 MB
    unsigned char* seg8 = (unsigned char*)alloc((size_t)N_EDGES);          // 1.2 MB
    _Float16* inv_e = (_Float16*)alloc((size_t)N_EDGES * 2);               // 2.4 MB
    _Float16* wf16 = (_Float16*)alloc((size_t)NLAYERS * GC * 160 * 2);     // 80 KB
    _Float16* ws16 = (_Float16*)alloc((size_t)NLAYERS * GC * 160 * 2);     // 80 KB
    int* row_st = (int*)alloc((size_t)(N_NODES + 1) * 4);
    float* inv_deg = (float*)alloc((size_t)N_NODES * 4);
    float* T = (float*)alloc((size_t)NATOM * GC * 4);
    int* bsums = (int*)alloc(512 * 4);
    int* boffs = (int*)alloc(512 * 4);
    const size_t ZR_INTS = (size_t)2 * N_NODES + 128 * NLAYERS + 64;
    char* zr = alloc(ZR_INTS * 4);
    int* deg = (int*)zr;
    int* cursor = deg + N_NODES;
    float* stats = (float*)(cursor + N_NODES);

    if ((size_t)(p - base) > ws_size) return;  // diagnostic bail

    (void)hipMemsetAsync(zr, 0, ZR_INTS * 4, stream);

    const int EG = (N_EDGES + 255) / 256;
    deg_kernel<<<EG, 256, 0, stream>>>(edge_index, deg);
    scan_a_kernel<<<391, 256, 0, stream>>>(deg, bsums);
    scan_b_kernel<<<1, 512, 0, stream>>>(bsums, boffs);
    scan_c_kernel<<<391, 256, 0, stream>>>(deg, boffs, row_st, inv_deg);
    scatter_perm_kernel<<<EG, 256, 0, stream>>>(edge_index, row_st, cursor, csr_src, csr_dst);
    rbf_kernel<<<EG, 256, 0, stream>>>(csr_src, csr_dst, pos, means, betas, ea);
    window_prep_kernel<<<(NWIN + 255) / 256, 256, 0, stream>>>(csr_dst, inv_deg, seg8, wnode, inv_e);
    wcvt_kernel<<<(NLAYERS * 160 * GC) / 256, 256, 0, stream>>>(Wf, Ws, wf16, ws16);
    atom_table_kernel<<<NATOM, 64, 0, stream>>>(emb, pre_W, pre_b, T);
    xinit_kernel<<<N_NODES * 16 / 256, 256, 0, stream>>>(atom_types, T, x, x16);

    for (int l = 0; l < NLAYERS; l++) {
        win_mfma_kernel<<<TILE_GRID, 256, 0, stream>>>(
            x16, (const _Float16*)ea, csr_src, csr_dst, seg8, wnode, inv_e,
            wf16 + (size_t)l * GC * 160, ws16 + (size_t)l * GC * 160,
            bf + l * GC, bs + l * GC, x);
        stats_kernel<<<256, 256, 0, stream>>>(x, stats + l * 128);
        if (l < NLAYERS - 1) {
            bn_x16_kernel<<<N_NODES * 16 / 256, 256, 0, stream>>>(
                x, stats + l * 128, gamma + l * GC, beta + l * GC, x, x16);
        } else {
            bn_kernel<<<N_NODES * 16 / 256, 256, 0, stream>>>(
                x, stats + l * 128, gamma + l * GC, beta + l * GC, (float*)d_out);
        }
    }
}